// Round 5
// baseline (329.853 us; speedup 1.0000x reference)
//
#include <hip/hip_runtime.h>
#include <math.h>

#define NB   128
#define CF   1024
#define RR   256
#define NA   312
#define DV   300
#define M2   320
#define MT   640
#define NKC  32

typedef _Float16 half8  __attribute__((ext_vector_type(8)));
typedef float float16v  __attribute__((ext_vector_type(16)));

// ---- K1: fused sumsq + raw f16 transpose; one block per (r-chunk, b) ----
// avT[b][kc][r][kk] = (f16) img[b][kc*32+kk][r]; invg[b][r] = 1/max(||img[b,:,r]||,eps)
__global__ void k_prep(const float* __restrict__ img, float* __restrict__ invg,
                       _Float16* __restrict__ avT) {
    int rc = blockIdx.x, b = blockIdx.y;
    int r0 = rc * 64;
    int t = threadIdx.x;
    __shared__ __align__(16) char sm[64 * 65 * 4];
    _Float16 (*tile)[65] = (_Float16 (*)[65])sm;
    float    (*ssb)[65]  = (float    (*)[65])sm;
    int fl = t >> 2, cg = t & 3;
    int rl = t >> 2, g  = t & 3;
    float ss[16];
    #pragma unroll
    for (int j = 0; j < 16; ++j) ss[j] = 0.f;

    for (int cc = 0; cc < 16; ++cc) {
        int f0 = cc * 64;
        const float4* p4 = (const float4*)(img + ((size_t)(b * CF + f0 + fl)) * RR + r0 + cg * 16);
        float4 v0 = p4[0], v1 = p4[1], v2 = p4[2], v3 = p4[3];
        __syncthreads();
        float xs[16] = {v0.x, v0.y, v0.z, v0.w, v1.x, v1.y, v1.z, v1.w,
                        v2.x, v2.y, v2.z, v2.w, v3.x, v3.y, v3.z, v3.w};
        #pragma unroll
        for (int j = 0; j < 16; ++j) {
            ss[j] += xs[j] * xs[j];
            tile[fl][cg * 16 + j] = (_Float16)xs[j];
        }
        __syncthreads();
        int kc  = (f0 >> 5) + (g >> 1);
        int kkb = (g & 1) * 16;
        half8 o0, o1;
        #pragma unroll
        for (int j = 0; j < 8; ++j) o0[j] = tile[g * 16 + j][rl];
        #pragma unroll
        for (int j = 0; j < 8; ++j) o1[j] = tile[g * 16 + 8 + j][rl];
        _Float16* q = avT + (((size_t)(b * NKC + kc) * RR + r0 + rl) * 32 + kkb);
        *(half8*)q       = o0;
        *(half8*)(q + 8) = o1;
    }
    __syncthreads();
    #pragma unroll
    for (int j = 0; j < 16; ++j) ssb[fl][cg * 16 + j] = ss[j];
    __syncthreads();
    if (t < 64) {
        float tot = 0.f;
        for (int f2 = 0; f2 < 64; ++f2) tot += ssb[f2][t];
        invg[b * RR + r0 + t] = 1.f / fmaxf(sqrtf(tot), 1e-12f);
    }
}

// ---- K2: Q = [l2norm(V)@W1 ; pad ; l2norm(V)@W2 ; pad] -> f16 Qb[kc][i][kk] ----
__global__ void k_q(const float* __restrict__ V, const float* __restrict__ W1,
                    const float* __restrict__ W2, _Float16* __restrict__ Qb) {
    int ib = blockIdx.x;
    int f  = blockIdx.y * 256 + threadIdx.x;
    int i0 = ib * 8;
    int t  = threadIdx.x;
    __shared__ float inv8[8];
    float acc[8] = {0,0,0,0,0,0,0,0};
    bool zero = (ib == 39 || ib == 79);
    int v0 = (ib < 40) ? i0 : i0 - M2;
    if (!zero) {
        int row = t >> 5, l32 = t & 31;
        float s = 0.f;
        for (int v = l32; v < DV; v += 32) { float x = V[(v0 + row) * DV + v]; s += x * x; }
        #pragma unroll
        for (int o = 16; o; o >>= 1) s += __shfl_xor(s, o, 32);
        if (l32 == 0) inv8[row] = 1.f / fmaxf(sqrtf(s), 1e-12f);
        __syncthreads();
        const float* W = (ib < 40) ? W1 : W2;
        for (int v = 0; v < DV; ++v) {
            float wv = W[(size_t)v * CF + f];
            #pragma unroll
            for (int ii = 0; ii < 8; ++ii) acc[ii] += V[(v0 + ii) * DV + v] * wv;
        }
        #pragma unroll
        for (int ii = 0; ii < 8; ++ii) acc[ii] *= inv8[ii];
    }
    #pragma unroll
    for (int ii = 0; ii < 8; ++ii)
        Qb[((size_t)(f >> 5) * MT + (i0 + ii)) * 32 + (f & 31)] = (_Float16)acc[ii];
}

// ---- K3: register-direct batched GEMM (no LDS staging, no K-loop barriers) ----
// Block = (t-pair t2, b): M=128 rows {t_a Q1/Q2, t_b Q1/Q2} x N=256.
// Wave w: all 128 rows x 64 cols [w*64, w*64+64). Frags loaded global->VGPR.
__launch_bounds__(256, 2)
__global__ void k_gemm(const _Float16* __restrict__ Qb, const _Float16* __restrict__ avT,
                       const float* __restrict__ invg, float* __restrict__ out) {
    int lin  = blockIdx.x;
    int xcd  = lin & 7;
    int slot = lin >> 3;
    int bq   = slot / 5;
    int t2   = slot - bq * 5;
    int b    = bq * 8 + xcd;

    int tid = threadIdx.x;
    int lane = tid & 63, w = tid >> 6;
    int nl = lane & 31, kh = lane >> 5;

    int rq1 = t2 * 64 + nl;        // Q1 rows of t_a (+32 -> t_b)
    int rq2 = M2 + t2 * 64 + nl;   // Q2 rows of t_a (+32 -> t_b)
    int cB  = w * 64 + nl;         // B cols (cb*32 offset for 2nd frag)

    __shared__ float mred[64 * 4];
    __shared__ float mg[64];
    __shared__ float sred[64 * 4];
    __shared__ float dred[64 * 4];

    float16v acc[4][2];   // [rf: Q1ta,Q2ta,Q1tb,Q2tb][cb]
    #pragma unroll
    for (int i = 0; i < 4; ++i)
        #pragma unroll
        for (int j = 0; j < 2; ++j)
            #pragma unroll
            for (int gi = 0; gi < 16; ++gi) acc[i][j][gi] = 0.f;

    half8 aA[8], bA[4], aB[8], bB[4];

    #define LOADF(Aa, Bb, kc_) do {                                              \
        const _Float16* ab = Qb + (size_t)(kc_) * MT * 32 + kh * 8;              \
        Aa[0] = *(const half8*)(ab + (size_t)rq1 * 32);                          \
        Aa[1] = *(const half8*)(ab + (size_t)rq1 * 32 + 16);                     \
        Aa[2] = *(const half8*)(ab + (size_t)rq2 * 32);                          \
        Aa[3] = *(const half8*)(ab + (size_t)rq2 * 32 + 16);                     \
        Aa[4] = *(const half8*)(ab + (size_t)(rq1 + 32) * 32);                   \
        Aa[5] = *(const half8*)(ab + (size_t)(rq1 + 32) * 32 + 16);              \
        Aa[6] = *(const half8*)(ab + (size_t)(rq2 + 32) * 32);                   \
        Aa[7] = *(const half8*)(ab + (size_t)(rq2 + 32) * 32 + 16);              \
        const _Float16* bb = avT + ((size_t)(b * NKC + (kc_)) * RR + cB) * 32 + kh * 8; \
        Bb[0] = *(const half8*)(bb);                                             \
        Bb[1] = *(const half8*)(bb + 16);                                        \
        Bb[2] = *(const half8*)(bb + 32 * 32);                                   \
        Bb[3] = *(const half8*)(bb + 32 * 32 + 16);                              \
    } while (0)

    #define COMP(Aa, Bb) do {                                                    \
        _Pragma("unroll")                                                        \
        for (int ks = 0; ks < 2; ++ks)                                           \
            _Pragma("unroll")                                                    \
            for (int rf = 0; rf < 4; ++rf)                                       \
                _Pragma("unroll")                                                \
                for (int cb = 0; cb < 2; ++cb)                                   \
                    acc[rf][cb] = __builtin_amdgcn_mfma_f32_32x32x16_f16(        \
                        Aa[rf * 2 + ks], Bb[cb * 2 + ks], acc[rf][cb], 0, 0, 0); \
    } while (0)

    LOADF(aA, bA, 0);
    for (int kc = 0; kc < NKC; kc += 2) {
        LOADF(aB, bB, kc + 1);
        COMP(aA, bA);
        if (kc + 2 < NKC) LOADF(aA, bA, kc + 2);
        COMP(aB, bB);
    }
    #undef LOADF
    #undef COMP

    // ---- epilogue: scale by inv[col], softmax over r, dot with Q2 rows ----
    float iv0 = invg[b * RR + w * 64 + nl];
    float iv1 = invg[b * RR + w * 64 + 32 + nl];
    #pragma unroll
    for (int rf = 0; rf < 4; ++rf)
        #pragma unroll
        for (int gi = 0; gi < 16; ++gi) {
            acc[rf][0][gi] *= iv0;
            acc[rf][1][gi] *= iv1;
        }

    // per-row max (pairs p: logits acc[2p], values acc[2p+1])
    float mx[2][16];
    #pragma unroll
    for (int p = 0; p < 2; ++p)
        #pragma unroll
        for (int gi = 0; gi < 16; ++gi)
            mx[p][gi] = fmaxf(acc[2 * p][0][gi], acc[2 * p][1][gi]);
    #pragma unroll
    for (int off = 1; off <= 16; off <<= 1)
        #pragma unroll
        for (int p = 0; p < 2; ++p)
            #pragma unroll
            for (int gi = 0; gi < 16; ++gi)
                mx[p][gi] = fmaxf(mx[p][gi], __shfl_xor(mx[p][gi], off, 64));
    if (nl == 0) {
        #pragma unroll
        for (int p = 0; p < 2; ++p)
            #pragma unroll
            for (int gi = 0; gi < 16; ++gi) {
                int row = (gi & 3) + 8 * (gi >> 2) + 4 * kh;
                mred[(p * 32 + row) * 4 + w] = mx[p][gi];
            }
    }
    __syncthreads();
    if (tid < 64)
        mg[tid] = fmaxf(fmaxf(mred[tid * 4], mred[tid * 4 + 1]),
                        fmaxf(mred[tid * 4 + 2], mred[tid * 4 + 3]));
    __syncthreads();
    float sp[2][16], dp[2][16];
    #pragma unroll
    for (int p = 0; p < 2; ++p)
        #pragma unroll
        for (int gi = 0; gi < 16; ++gi) {
            int row = (gi & 3) + 8 * (gi >> 2) + 4 * kh;
            float m  = mg[p * 32 + row];
            float e0 = __expf(acc[2 * p][0][gi] - m);
            float e1 = __expf(acc[2 * p][1][gi] - m);
            sp[p][gi] = e0 + e1;
            dp[p][gi] = e0 * acc[2 * p + 1][0][gi] + e1 * acc[2 * p + 1][1][gi];
        }
    #pragma unroll
    for (int off = 1; off <= 16; off <<= 1)
        #pragma unroll
        for (int p = 0; p < 2; ++p)
            #pragma unroll
            for (int gi = 0; gi < 16; ++gi) {
                sp[p][gi] += __shfl_xor(sp[p][gi], off, 64);
                dp[p][gi] += __shfl_xor(dp[p][gi], off, 64);
            }
    if (nl == 0) {
        #pragma unroll
        for (int p = 0; p < 2; ++p)
            #pragma unroll
            for (int gi = 0; gi < 16; ++gi) {
                int row = (gi & 3) + 8 * (gi >> 2) + 4 * kh;
                sred[(p * 32 + row) * 4 + w] = sp[p][gi];
                dred[(p * 32 + row) * 4 + w] = dp[p][gi];
            }
    }
    __syncthreads();
    if (tid < 64) {
        float s = sred[tid * 4] + sred[tid * 4 + 1] + sred[tid * 4 + 2] + sred[tid * 4 + 3];
        float d = dred[tid * 4] + dred[tid * 4 + 1] + dred[tid * 4 + 2] + dred[tid * 4 + 3];
        int ig = t2 * 64 + tid;
        if (ig < NA) out[b * NA + ig] = d / s;
    }
}

// ---- launcher ----
extern "C" void kernel_launch(void* const* d_in, const int* in_sizes, int n_in,
                              void* d_out, int out_size, void* d_ws, size_t ws_size,
                              hipStream_t stream) {
    const float* img = (const float*)d_in[0];
    const float* V   = (const float*)d_in[1];
    const float* W1  = (const float*)d_in[2];
    const float* W2  = (const float*)d_in[3];
    float* out = (float*)d_out;

    char* ws = (char*)d_ws;
    size_t off = 0;
    float*    invg = (float*)(ws + off);    off += (size_t)NB * RR * 4;
    _Float16* avT  = (_Float16*)(ws + off); off += (size_t)NB * CF * RR * 2;
    _Float16* Qb   = (_Float16*)(ws + off); off += (size_t)NKC * MT * 32 * 2;

    k_prep<<<dim3(4, NB), 256, 0, stream>>>(img, invg, avT);
    k_q<<<dim3(80, 4), 256, 0, stream>>>(V, W1, W2, Qb);
    k_gemm<<<dim3(640), 256, 0, stream>>>(Qb, avT, invg, out);
}

// Round 6
// 321.532 us; speedup vs baseline: 1.0259x; 1.0259x over previous
//
#include <hip/hip_runtime.h>
#include <math.h>

#define NB   128
#define CF   1024
#define RR   256
#define NA   312
#define DV   300
#define M2   320
#define MT   640
#define NKC  32

typedef _Float16 half8  __attribute__((ext_vector_type(8)));
typedef float float16v  __attribute__((ext_vector_type(16)));

__device__ __forceinline__ void gload16(const void* g, void* l) {
    __builtin_amdgcn_global_load_lds(
        (const __attribute__((address_space(1))) void*)g,
        (__attribute__((address_space(3))) void*)l, 16, 0, 0);
}

// ---- K1: fused sumsq + raw f16 transpose; one block per (r-chunk, b) ----
// avT[b][kc][r][kk] = (f16) img[b][kc*32+kk][r]; invg[b][r] = 1/max(||img[b,:,r]||,eps)
__global__ void k_prep(const float* __restrict__ img, float* __restrict__ invg,
                       _Float16* __restrict__ avT) {
    int rc = blockIdx.x, b = blockIdx.y;
    int r0 = rc * 64;
    int t = threadIdx.x;
    __shared__ __align__(16) char sm[64 * 65 * 4];
    _Float16 (*tile)[65] = (_Float16 (*)[65])sm;
    float    (*ssb)[65]  = (float    (*)[65])sm;
    int fl = t >> 2, cg = t & 3;
    int rl = t >> 2, g  = t & 3;
    float ss[16];
    #pragma unroll
    for (int j = 0; j < 16; ++j) ss[j] = 0.f;

    for (int cc = 0; cc < 16; ++cc) {
        int f0 = cc * 64;
        const float4* p4 = (const float4*)(img + ((size_t)(b * CF + f0 + fl)) * RR + r0 + cg * 16);
        float4 v0 = p4[0], v1 = p4[1], v2 = p4[2], v3 = p4[3];
        __syncthreads();
        float xs[16] = {v0.x, v0.y, v0.z, v0.w, v1.x, v1.y, v1.z, v1.w,
                        v2.x, v2.y, v2.z, v2.w, v3.x, v3.y, v3.z, v3.w};
        #pragma unroll
        for (int j = 0; j < 16; ++j) {
            ss[j] += xs[j] * xs[j];
            tile[fl][cg * 16 + j] = (_Float16)xs[j];
        }
        __syncthreads();
        int kc  = (f0 >> 5) + (g >> 1);
        int kkb = (g & 1) * 16;
        half8 o0, o1;
        #pragma unroll
        for (int j = 0; j < 8; ++j) o0[j] = tile[g * 16 + j][rl];
        #pragma unroll
        for (int j = 0; j < 8; ++j) o1[j] = tile[g * 16 + 8 + j][rl];
        _Float16* q = avT + (((size_t)(b * NKC + kc) * RR + r0 + rl) * 32 + kkb);
        *(half8*)q       = o0;
        *(half8*)(q + 8) = o1;
    }
    __syncthreads();
    #pragma unroll
    for (int j = 0; j < 16; ++j) ssb[fl][cg * 16 + j] = ss[j];
    __syncthreads();
    if (t < 64) {
        float tot = 0.f;
        for (int f2 = 0; f2 < 64; ++f2) tot += ssb[f2][t];
        invg[b * RR + r0 + t] = 1.f / fmaxf(sqrtf(tot), 1e-12f);
    }
}

// ---- K2: Q = [l2norm(V)@W1 ; pad ; l2norm(V)@W2 ; pad] -> f16 Qb[kc][i][kk] ----
__global__ void k_q(const float* __restrict__ V, const float* __restrict__ W1,
                    const float* __restrict__ W2, _Float16* __restrict__ Qb) {
    int ib = blockIdx.x;
    int f  = blockIdx.y * 256 + threadIdx.x;
    int i0 = ib * 8;
    int t  = threadIdx.x;
    __shared__ float inv8[8];
    float acc[8] = {0,0,0,0,0,0,0,0};
    bool zero = (ib == 39 || ib == 79);
    int v0 = (ib < 40) ? i0 : i0 - M2;
    if (!zero) {
        int row = t >> 5, l32 = t & 31;
        float s = 0.f;
        for (int v = l32; v < DV; v += 32) { float x = V[(v0 + row) * DV + v]; s += x * x; }
        #pragma unroll
        for (int o = 16; o; o >>= 1) s += __shfl_xor(s, o, 32);
        if (l32 == 0) inv8[row] = 1.f / fmaxf(sqrtf(s), 1e-12f);
        __syncthreads();
        const float* W = (ib < 40) ? W1 : W2;
        for (int v = 0; v < DV; ++v) {
            float wv = W[(size_t)v * CF + f];
            #pragma unroll
            for (int ii = 0; ii < 8; ++ii) acc[ii] += V[(v0 + ii) * DV + v] * wv;
        }
        #pragma unroll
        for (int ii = 0; ii < 8; ++ii) acc[ii] *= inv8[ii];
    }
    #pragma unroll
    for (int ii = 0; ii < 8; ++ii)
        Qb[((size_t)(f >> 5) * MT + (i0 + ii)) * 32 + (f & 31)] = (_Float16)acc[ii];
}

// ---- K3: batched GEMM, M=128 x N=256 per block, LDS-DMA double buffer ----
// Tile rows 0-63 = Q1 rows t2*64.., rows 64-127 = Q2 rows M2+t2*64..
__launch_bounds__(256, 2)
__global__ void k_gemm(const _Float16* __restrict__ Qb, const _Float16* __restrict__ avT,
                       const float* __restrict__ invg, float* __restrict__ out) {
    int lin  = blockIdx.x;
    int xcd  = lin & 7;
    int slot = lin >> 3;
    int bq   = slot / 5;
    int t2   = slot - bq * 5;     // 0..4
    int b    = bq * 8 + xcd;

    int tid = threadIdx.x;
    int lane = tid & 63, w = tid >> 6;
    int nl = lane & 31, kh = lane >> 5;

    // LDS: A0@0 (8K), A1@8K (8K), B0@16K (16K), B1@32K (16K) = 48 KB
    __shared__ __align__(16) char smem[49152];
    _Float16* A0 = (_Float16*)smem;
    _Float16* A1 = (_Float16*)(smem + 8192);
    _Float16* B0 = (_Float16*)(smem + 16384);
    _Float16* B1 = (_Float16*)(smem + 32768);
    // epilogue overlays (inside dead A0/A1 region, used only after k-loop):
    float* mred = (float*)smem;            // [64][4]
    float* mg   = (float*)(smem + 1024);   // [64]
    float* sred = (float*)(smem + 1280);   // [64][4]
    float* dred = (float*)(smem + 2304);   // [64][4]

    float16v acc[4][2];   // [rf: Q1a,Q1b,Q2a,Q2b][cb]
    #pragma unroll
    for (int i = 0; i < 4; ++i)
        #pragma unroll
        for (int j = 0; j < 2; ++j)
            #pragma unroll
            for (int gi = 0; gi < 16; ++gi) acc[i][j][gi] = 0.f;

    // per-thread DMA offsets (elements)
    int arow  = tid & 127;                       // tile row
    int akb0  = tid >> 7;                        // k-block for round 0 (0/1)
    int grow  = (arow < 64) ? (t2 * 64 + arow) : (M2 + t2 * 64 + (arow - 64));
    size_t a_src0 = (size_t)grow * 32 + akb0 * 8;        // + kc*MT*32
    size_t a_dst0 = ((size_t)akb0 * 128 + arow) * 8;     // A LDS [kb][row][8]
    // round 1: kb += 2 -> src +16 elems, dst +2048 elems
    size_t b_src0 = (size_t)tid * 32;                    // + kc*RR*32 + rd*8
    size_t b_dst0 = (size_t)tid * 8;                     // + rd*2048
    const _Float16* bpanel = avT + (size_t)b * NKC * RR * 32;

    #define STAGE(kc_, Ad, Bd) do {                                             \
        const _Float16* as = Qb + (size_t)(kc_) * MT * 32;                      \
        gload16(as + a_src0,      (Ad) + a_dst0);                               \
        gload16(as + a_src0 + 16, (Ad) + a_dst0 + 2048);                        \
        const _Float16* bs = bpanel + (size_t)(kc_) * RR * 32;                  \
        gload16(bs + b_src0 + 0 * 8, (Bd) + b_dst0 + 0 * 2048);                 \
        gload16(bs + b_src0 + 1 * 8, (Bd) + b_dst0 + 1 * 2048);                 \
        gload16(bs + b_src0 + 2 * 8, (Bd) + b_dst0 + 2 * 2048);                 \
        gload16(bs + b_src0 + 3 * 8, (Bd) + b_dst0 + 3 * 2048);                 \
    } while (0)

    #define COMPUTE(Al, Bl) do {                                                \
        _Pragma("unroll")                                                       \
        for (int ks = 0; ks < 2; ++ks) {                                        \
            int kb = ks * 2 + kh;                                               \
            half8 b0f = *(const half8*)((Bl) + ((size_t)kb * 256 + w * 64 + nl) * 8);       \
            half8 b1f = *(const half8*)((Bl) + ((size_t)kb * 256 + w * 64 + 32 + nl) * 8);  \
            _Pragma("unroll")                                                   \
            for (int rf = 0; rf < 4; ++rf) {                                    \
                half8 af = *(const half8*)((Al) + ((size_t)kb * 128 + rf * 32 + nl) * 8);   \
                acc[rf][0] = __builtin_amdgcn_mfma_f32_32x32x16_f16(af, b0f, acc[rf][0], 0, 0, 0); \
                acc[rf][1] = __builtin_amdgcn_mfma_f32_32x32x16_f16(af, b1f, acc[rf][1], 0, 0, 0); \
            }                                                                   \
        }                                                                       \
    } while (0)

    STAGE(0, A0, B0);
    for (int kc = 0; kc < NKC; kc += 2) {
        __syncthreads();                 // buf0 (kc) staged; buf1 readers done
        STAGE(kc + 1, A1, B1);
        COMPUTE(A0, B0);
        __syncthreads();                 // buf1 (kc+1) staged; buf0 readers done
        if (kc + 2 < NKC) STAGE(kc + 2, A0, B0);
        COMPUTE(A1, B1);
    }
    __syncthreads();                     // overlay safe
    #undef STAGE
    #undef COMPUTE

    // ---- epilogue: scale by inv[col], softmax over r (pairs p: rf=p logits, rf=p+2 values) ----
    float iv0 = invg[b * RR + w * 64 + nl];
    float iv1 = invg[b * RR + w * 64 + 32 + nl];
    #pragma unroll
    for (int rf = 0; rf < 4; ++rf)
        #pragma unroll
        for (int gi = 0; gi < 16; ++gi) {
            acc[rf][0][gi] *= iv0;
            acc[rf][1][gi] *= iv1;
        }

    float mx[2][16];
    #pragma unroll
    for (int p = 0; p < 2; ++p)
        #pragma unroll
        for (int gi = 0; gi < 16; ++gi)
            mx[p][gi] = fmaxf(acc[p][0][gi], acc[p][1][gi]);
    #pragma unroll
    for (int off = 1; off <= 16; off <<= 1)
        #pragma unroll
        for (int p = 0; p < 2; ++p)
            #pragma unroll
            for (int gi = 0; gi < 16; ++gi)
                mx[p][gi] = fmaxf(mx[p][gi], __shfl_xor(mx[p][gi], off, 64));
    if (nl == 0) {
        #pragma unroll
        for (int p = 0; p < 2; ++p)
            #pragma unroll
            for (int gi = 0; gi < 16; ++gi) {
                int row = (gi & 3) + 8 * (gi >> 2) + 4 * kh;
                mred[(p * 32 + row) * 4 + w] = mx[p][gi];
            }
    }
    __syncthreads();
    if (tid < 64)
        mg[tid] = fmaxf(fmaxf(mred[tid * 4], mred[tid * 4 + 1]),
                        fmaxf(mred[tid * 4 + 2], mred[tid * 4 + 3]));
    __syncthreads();
    float sp[2][16], dp[2][16];
    #pragma unroll
    for (int p = 0; p < 2; ++p)
        #pragma unroll
        for (int gi = 0; gi < 16; ++gi) {
            int row = (gi & 3) + 8 * (gi >> 2) + 4 * kh;
            float m  = mg[p * 32 + row];
            float e0 = __expf(acc[p][0][gi] - m);
            float e1 = __expf(acc[p][1][gi] - m);
            sp[p][gi] = e0 + e1;
            dp[p][gi] = e0 * acc[p + 2][0][gi] + e1 * acc[p + 2][1][gi];
        }
    #pragma unroll
    for (int off = 1; off <= 16; off <<= 1)
        #pragma unroll
        for (int p = 0; p < 2; ++p)
            #pragma unroll
            for (int gi = 0; gi < 16; ++gi) {
                sp[p][gi] += __shfl_xor(sp[p][gi], off, 64);
                dp[p][gi] += __shfl_xor(dp[p][gi], off, 64);
            }
    if (nl == 0) {
        #pragma unroll
        for (int p = 0; p < 2; ++p)
            #pragma unroll
            for (int gi = 0; gi < 16; ++gi) {
                int row = (gi & 3) + 8 * (gi >> 2) + 4 * kh;
                sred[(p * 32 + row) * 4 + w] = sp[p][gi];
                dred[(p * 32 + row) * 4 + w] = dp[p][gi];
            }
    }
    __syncthreads();
    if (tid < 64) {
        float s = sred[tid * 4] + sred[tid * 4 + 1] + sred[tid * 4 + 2] + sred[tid * 4 + 3];
        float d = dred[tid * 4] + dred[tid * 4 + 1] + dred[tid * 4 + 2] + dred[tid * 4 + 3];
        int ig = t2 * 64 + tid;
        if (ig < NA) out[b * NA + ig] = d / s;
    }
}

// ---- launcher ----
extern "C" void kernel_launch(void* const* d_in, const int* in_sizes, int n_in,
                              void* d_out, int out_size, void* d_ws, size_t ws_size,
                              hipStream_t stream) {
    const float* img = (const float*)d_in[0];
    const float* V   = (const float*)d_in[1];
    const float* W1  = (const float*)d_in[2];
    const float* W2  = (const float*)d_in[3];
    float* out = (float*)d_out;

    char* ws = (char*)d_ws;
    size_t off = 0;
    float*    invg = (float*)(ws + off);    off += (size_t)NB * RR * 4;
    _Float16* avT  = (_Float16*)(ws + off); off += (size_t)NB * CF * RR * 2;
    _Float16* Qb   = (_Float16*)(ws + off); off += (size_t)NKC * MT * 32 * 2;

    k_prep<<<dim3(4, NB), 256, 0, stream>>>(img, invg, avT);
    k_q<<<dim3(80, 4), 256, 0, stream>>>(V, W1, W2, Qb);
    k_gemm<<<dim3(640), 256, 0, stream>>>(Qb, avT, invg, out);
}